// Round 13
// baseline (122.000 us; speedup 1.0000x reference)
//
#include <hip/hip_runtime.h>

#define ROWS 8
#define N 4096
#define BATCH 8192
#define S_AB 264            // arena row stride (floats): 256+8
#define ARENA 4224          // floats per arena (16*264); 2 arenas = 33792 B
#define NWS_F4 (8 * 2048)   // permuted twiddles, layers 4..11

typedef float v4f __attribute__((ext_vector_type(4)));

__device__ __forceinline__ void layer_compute(float (&v)[ROWS][16],
                                              const float4 (&w)[8],
                                              const int bit) {
    const int d = 1 << bit;
    #pragma unroll
    for (int pc = 0; pc < 8; ++pc) {
        const int lo = ((pc >> bit) << (bit + 1)) | (pc & (d - 1));
        const int hi = lo + d;
        #pragma unroll
        for (int r = 0; r < ROWS; ++r) {
            const float top = v[r][lo];
            const float bot = v[r][hi];
            v[r][lo] = w[pc].x * top + w[pc].y * bot;
            v[r][hi] = w[pc].z * top + w[pc].w * bot;
        }
    }
}

// ---- Prepass (unchanged): layers 4..11 -> lane-coalesced nws.
__global__ __launch_bounds__(256)
void permute_tw_kernel(const float* __restrict__ tw, float4* __restrict__ nws) {
    const int i = blockIdx.x * 256 + threadIdx.x;   // 0 .. 16383
    const int s  = i >> 11;                         // slot 0..7 -> layer 4+s
    const int j  = i & 2047;
    const int pc = j >> 8;
    const int a  = (j >> 4) & 15;
    const int cb = j & 15;
    const float4* tw4 = (const float4*)tw;
    const int src = (s < 4) ? (a * 128 + pc * 16 + cb)   // stage B layers 4..7
                            : (a * 128 + cb * 8 + pc);   // stage C layers 8..11
    nws[i] = tw4[(4 + s) * 2048 + src];
}

// ROWS=8: one block's 96 float4 twiddle loads/thread now serve 8 rows (was 4)
// -> per-row twiddle VMEM instructions and L2 twiddle traffic halve (805->402
// MB). This is the only remaining lever in the proven currency (R3/R9/R12:
// only VMEM request cuts move time). launch_bounds(256,1): VGPR cap 256 by
// the empirical ~256/min_waves law; peak live ~170-180 (128 data + temps).
__global__ __launch_bounds__(256, 1)
void butterfly_kernel(const float* __restrict__ x,
                      const float* __restrict__ tw,
                      const float4* __restrict__ nws,
                      float* __restrict__ out) {
    __shared__ float lds[2 * ARENA];
    float* bufA = lds;
    float* bufB = lds + ARENA;
    const int t   = threadIdx.x;
    const int thi = t >> 4;
    const int tlo = t & 15;
    const int row0 = blockIdx.x * ROWS;
    const float4* tw4 = (const float4*)tw;

    float v[ROWS][16];

    // ---- Stage-in: 4 batches of 2 rows through linear LDS; next batch's
    // global loads are issued before the barrier so HBM latency flies over it.
    {
        v4f t0[4], t1[4];
        const float* r0 = x + (size_t)(row0 + 0) * N + 4 * t;
        const float* r1 = x + (size_t)(row0 + 1) * N + 4 * t;
        #pragma unroll
        for (int i = 0; i < 4; ++i) t0[i] = *(const v4f*)(r0 + i * 1024);
        #pragma unroll
        for (int i = 0; i < 4; ++i) t1[i] = *(const v4f*)(r1 + i * 1024);
        #pragma unroll
        for (int p = 0; p < 4; ++p) {
            #pragma unroll
            for (int i = 0; i < 4; ++i) *(v4f*)(bufA + i * 1024 + 4 * t) = t0[i];
            #pragma unroll
            for (int i = 0; i < 4; ++i) *(v4f*)(bufB + i * 1024 + 4 * t) = t1[i];
            if (p < 3) {
                const float* ra = x + (size_t)(row0 + 2 * p + 2) * N + 4 * t;
                const float* rb = x + (size_t)(row0 + 2 * p + 3) * N + 4 * t;
                #pragma unroll
                for (int i = 0; i < 4; ++i) t0[i] = *(const v4f*)(ra + i * 1024);
                #pragma unroll
                for (int i = 0; i < 4; ++i) t1[i] = *(const v4f*)(rb + i * 1024);
            }
            __syncthreads();
            #pragma unroll
            for (int a = 0; a < 16; ++a) v[2 * p][a]     = bufA[a * 256 + t];
            #pragma unroll
            for (int a = 0; a < 16; ++a) v[2 * p + 1][a] = bufB[a * 256 + t];
            __syncthreads();
        }
    }

    // ---- Stage A: layers 0..3 (pairs in a); natural twiddle layout coalesced
    #pragma unroll
    for (int l = 0; l < 4; ++l) {
        float4 w[8];
        #pragma unroll
        for (int pc = 0; pc < 8; ++pc)
            w[pc] = tw4[l * 2048 + pc * 256 + t];
        layer_compute(v, w, 3 - l);
    }

    // ---- Transpose A->B, 4 batches of 2 rows (write stride-1, read 2-way: free)
    #pragma unroll
    for (int p = 0; p < 4; ++p) {
        #pragma unroll
        for (int a = 0; a < 16; ++a) {
            bufA[a * S_AB + t] = v[2 * p][a];
            bufB[a * S_AB + t] = v[2 * p + 1][a];
        }
        __syncthreads();
        #pragma unroll
        for (int b = 0; b < 16; ++b) {
            v[2 * p][b]     = bufA[thi * S_AB + b * 16 + tlo];
            v[2 * p + 1][b] = bufB[thi * S_AB + b * 16 + tlo];
        }
        __syncthreads();
    }

    // ---- Stage B: layers 4..7 (pairs in b); coalesced permuted twiddles
    #pragma unroll
    for (int l = 4; l < 8; ++l) {
        float4 w[8];
        #pragma unroll
        for (int pc = 0; pc < 8; ++pc)
            w[pc] = nws[(l - 4) * 2048 + pc * 256 + t];
        layer_compute(v, w, 3 - (l - 4));
    }

    // ---- Transpose B->C, compact q-XOR layout (proven R12): elem (a,b,c) at
    // a*264 + b*16 + 4*((c>>2)^(b&3)) + (c&3); writes 2-way free, b128 reads
    // spread over all 8 base slots.
    #pragma unroll
    for (int p = 0; p < 4; ++p) {
        #pragma unroll
        for (int b = 0; b < 16; ++b) {
            const int coff = 4 * (((tlo >> 2) ^ (b & 3))) + (tlo & 3);
            bufA[thi * S_AB + b * 16 + coff] = v[2 * p][b];
            bufB[thi * S_AB + b * 16 + coff] = v[2 * p + 1][b];
        }
        __syncthreads();
        #pragma unroll
        for (int rr = 0; rr < 2; ++rr) {
            const float* bp = (rr ? bufB : bufA) + thi * S_AB + tlo * 16;
            #pragma unroll
            for (int q = 0; q < 4; ++q) {
                v4f c4 = *(const v4f*)(bp + 4 * (q ^ (tlo & 3)));
                v[2 * p + rr][4 * q + 0] = c4.x; v[2 * p + rr][4 * q + 1] = c4.y;
                v[2 * p + rr][4 * q + 2] = c4.z; v[2 * p + rr][4 * q + 3] = c4.w;
            }
        }
        __syncthreads();
    }

    // ---- Stage C: layers 8..11 (pairs in c)
    #pragma unroll
    for (int l = 8; l < 12; ++l) {
        float4 w[8];
        #pragma unroll
        for (int pc = 0; pc < 8; ++pc)
            w[pc] = nws[(l - 4) * 2048 + pc * 256 + t];
        layer_compute(v, w, 3 - (l - 8));
    }

    // ---- Store restage (proven R12 XOR layout), 4 batches of 2 rows:
    // writer f4[4T + (Q^((T>>2)&3))], reader f4[(j&~3)|((j&3)^((j>>4)&3))],
    // both 8 lanes/slot (free); then 1KB/wave contiguous nontemporal stores.
    {
        v4f* fA = (v4f*)bufA;
        v4f* fB = (v4f*)bufB;
        const int wsel = (t >> 2) & 3;
        #pragma unroll
        for (int p = 0; p < 4; ++p) {
            #pragma unroll
            for (int rr = 0; rr < 2; ++rr) {
                v4f* f = rr ? fB : fA;
                const int r = 2 * p + rr;
                #pragma unroll
                for (int q = 0; q < 4; ++q) {
                    v4f s4;
                    s4.x = v[r][4 * q + 0]; s4.y = v[r][4 * q + 1];
                    s4.z = v[r][4 * q + 2]; s4.w = v[r][4 * q + 3];
                    f[4 * t + (q ^ wsel)] = s4;
                }
            }
            __syncthreads();
            #pragma unroll
            for (int rr = 0; rr < 2; ++rr) {
                v4f* f = rr ? fB : fA;
                const int r = 2 * p + rr;
                float* orow = out + (size_t)(row0 + r) * N;
                #pragma unroll
                for (int k = 0; k < 4; ++k) {
                    const int j = k * 256 + t;
                    v4f s4 = f[(j & ~3) | ((j & 3) ^ ((j >> 4) & 3))];
                    __builtin_nontemporal_store(s4, (v4f*)orow + j);
                }
            }
            if (p < 3) __syncthreads();
        }
    }
}

// ---- Fallback (R6 structure) if workspace too small for the prepass
#define PAD_STRIDE 264
#define BUF_WORDS (16 * PAD_STRIDE)

__device__ __forceinline__ void layer16(float (&v)[4][16], const float4 (&w)[8], const int bit) {
    const int d = 1 << bit;
    #pragma unroll
    for (int pc = 0; pc < 8; ++pc) {
        const int lo = ((pc >> bit) << (bit + 1)) | (pc & (d - 1));
        const int hi = lo + d;
        #pragma unroll
        for (int r = 0; r < 4; ++r) {
            const float top = v[r][lo], bot = v[r][hi];
            v[r][lo] = w[pc].x * top + w[pc].y * bot;
            v[r][hi] = w[pc].z * top + w[pc].w * bot;
        }
    }
}

__global__ __launch_bounds__(256, 3)
void butterfly_kernel_fb(const float* __restrict__ x,
                         const float* __restrict__ tw,
                         float* __restrict__ out) {
    __shared__ float lds[BUF_WORDS];
    const int t = threadIdx.x;
    const int thi = t >> 4, tlo = t & 15;
    const int row0 = blockIdx.x * 4;
    const float4* tw4 = (const float4*)tw;
    float v[4][16];
    #pragma unroll
    for (int r = 0; r < 4; ++r) {
        const float* xr = x + (size_t)(row0 + r) * N + t;
        #pragma unroll
        for (int a = 0; a < 16; ++a) v[r][a] = __builtin_nontemporal_load(xr + a * 256);
    }
    #pragma unroll
    for (int l = 0; l < 4; ++l) {
        float4 w[8];
        #pragma unroll
        for (int pc = 0; pc < 8; ++pc) w[pc] = tw4[l * 2048 + pc * 256 + t];
        layer16(v, w, 3 - l);
    }
    #pragma unroll
    for (int r = 0; r < 4; ++r) {
        #pragma unroll
        for (int a = 0; a < 16; ++a) lds[a * PAD_STRIDE + t] = v[r][a];
        __syncthreads();
        #pragma unroll
        for (int b = 0; b < 16; ++b) v[r][b] = lds[thi * PAD_STRIDE + b * 16 + tlo];
        __syncthreads();
    }
    #pragma unroll
    for (int l = 4; l < 8; ++l) {
        float4 w[8];
        #pragma unroll
        for (int pc = 0; pc < 8; ++pc) w[pc] = tw4[l * 2048 + thi * 128 + pc * 16 + tlo];
        layer16(v, w, 3 - (l - 4));
    }
    #pragma unroll
    for (int r = 0; r < 4; ++r) {
        #pragma unroll
        for (int b = 0; b < 16; ++b) lds[thi * PAD_STRIDE + b * 16 + tlo] = v[r][b];
        __syncthreads();
        const float* bp = &lds[thi * PAD_STRIDE + tlo * 16];
        #pragma unroll
        for (int q = 0; q < 4; ++q) {
            v4f c4 = *(const v4f*)(bp + 4 * q);
            v[r][4 * q + 0] = c4.x; v[r][4 * q + 1] = c4.y;
            v[r][4 * q + 2] = c4.z; v[r][4 * q + 3] = c4.w;
        }
        if (r != 3) __syncthreads();
    }
    #pragma unroll
    for (int l = 8; l < 12; ++l) {
        float4 w[8];
        #pragma unroll
        for (int pc = 0; pc < 8; ++pc) w[pc] = tw4[l * 2048 + thi * 128 + tlo * 8 + pc];
        layer16(v, w, 3 - (l - 8));
    }
    #pragma unroll
    for (int r = 0; r < 4; ++r) {
        float* orow = out + (size_t)(row0 + r) * N + 16 * t;
        #pragma unroll
        for (int q = 0; q < 4; ++q) {
            v4f s4;
            s4.x = v[r][4 * q + 0]; s4.y = v[r][4 * q + 1];
            s4.z = v[r][4 * q + 2]; s4.w = v[r][4 * q + 3];
            *(v4f*)(orow + 4 * q) = s4;
        }
    }
}

extern "C" void kernel_launch(void* const* d_in, const int* in_sizes, int n_in,
                              void* d_out, int out_size, void* d_ws, size_t ws_size,
                              hipStream_t stream) {
    const float* x  = (const float*)d_in[0];
    const float* tw = (const float*)d_in[1];
    float* out      = (float*)d_out;
    dim3 block(256);
    if (ws_size >= (size_t)NWS_F4 * 16u) {
        float4* nws = (float4*)d_ws;
        hipLaunchKernelGGL(permute_tw_kernel, dim3(64), block, 0, stream, tw, nws);
        hipLaunchKernelGGL(butterfly_kernel, dim3(BATCH / ROWS), block, 0, stream,
                           x, tw, nws, out);
    } else {
        hipLaunchKernelGGL(butterfly_kernel_fb, dim3(BATCH / 4), block, 0, stream,
                           x, tw, out);
    }
}

// Round 14
// 90.283 us; speedup vs baseline: 1.3513x; 1.3513x over previous
//
#include <hip/hip_runtime.h>

#define ROWS 4
#define N 4096
#define BATCH 8192
#define S_AB 264            // arena row stride (floats): 256+8
#define ARENA 4224          // floats per arena (16*264); 2 arenas = 33792 B
#define NWS_F4 (8 * 2048)   // permuted twiddles, layers 4..11

typedef float v4f __attribute__((ext_vector_type(4)));

__device__ __forceinline__ void layer_compute(float (&v)[ROWS][16],
                                              const float4 (&w)[8],
                                              const int bit) {
    const int d = 1 << bit;
    #pragma unroll
    for (int pc = 0; pc < 8; ++pc) {
        const int lo = ((pc >> bit) << (bit + 1)) | (pc & (d - 1));
        const int hi = lo + d;
        #pragma unroll
        for (int r = 0; r < ROWS; ++r) {
            const float top = v[r][lo];
            const float bot = v[r][hi];
            v[r][lo] = w[pc].x * top + w[pc].y * bot;
            v[r][hi] = w[pc].z * top + w[pc].w * bot;
        }
    }
}

// ---- Prepass (unchanged): layers 4..11 -> lane-coalesced nws.
__global__ __launch_bounds__(256)
void permute_tw_kernel(const float* __restrict__ tw, float4* __restrict__ nws) {
    const int i = blockIdx.x * 256 + threadIdx.x;   // 0 .. 16383
    const int s  = i >> 11;                         // slot 0..7 -> layer 4+s
    const int j  = i & 2047;
    const int pc = j >> 8;
    const int a  = (j >> 4) & 15;
    const int cb = j & 15;
    const float4* tw4 = (const float4*)tw;
    const int src = (s < 4) ? (a * 128 + pc * 16 + cb)   // stage B layers 4..7
                            : (a * 128 + cb * 8 + pc);   // stage C layers 8..11
    nws[i] = tw4[(4 + s) * 2048 + src];
}

// R12 structure (best: 66.7us) minus the store restage. ROWS=4 / 84-VGPR /
// (256,3) is the proven sweet spot: R13's ROWS=8 (132 VGPR, no spill) dropped
// occupancy to ~1 block/CU and doubled time -> need >=2 blocks/CU for phase
// overlap. Store restage (R9) was bundled with the twiddle prepass and never
// isolated; R3 proved direct 64B-lane-stride write-back stores merge cleanly
// in L2 (WRITE 139MB), and the request-rate wall is now slack (~0.47/cy).
__global__ __launch_bounds__(256, 3)
void butterfly_kernel(const float* __restrict__ x,
                      const float* __restrict__ tw,
                      const float4* __restrict__ nws,
                      float* __restrict__ out) {
    __shared__ float lds[2 * ARENA];
    float* bufA = lds;
    float* bufB = lds + ARENA;
    const int t   = threadIdx.x;
    const int thi = t >> 4;
    const int tlo = t & 15;
    const int row0 = blockIdx.x * ROWS;
    const float4* tw4 = (const float4*)tw;

    float v[ROWS][16];

    // ---- Stage-in: 16 dwordx4 global requests/thread through linear LDS;
    // rows 2/3 loads issued before barrier 1 so HBM latency flies over it.
    {
        const float* r0 = x + (size_t)(row0 + 0) * N + 4 * t;
        const float* r1 = x + (size_t)(row0 + 1) * N + 4 * t;
        const float* r2 = x + (size_t)(row0 + 2) * N + 4 * t;
        const float* r3 = x + (size_t)(row0 + 3) * N + 4 * t;
        v4f t0[4], t1[4];
        #pragma unroll
        for (int i = 0; i < 4; ++i) t0[i] = *(const v4f*)(r0 + i * 1024);
        #pragma unroll
        for (int i = 0; i < 4; ++i) t1[i] = *(const v4f*)(r1 + i * 1024);
        #pragma unroll
        for (int i = 0; i < 4; ++i) *(v4f*)(bufA + i * 1024 + 4 * t) = t0[i];
        #pragma unroll
        for (int i = 0; i < 4; ++i) *(v4f*)(bufB + i * 1024 + 4 * t) = t1[i];
        #pragma unroll
        for (int i = 0; i < 4; ++i) t0[i] = *(const v4f*)(r2 + i * 1024);  // in flight
        #pragma unroll
        for (int i = 0; i < 4; ++i) t1[i] = *(const v4f*)(r3 + i * 1024);  // across bars
        __syncthreads();
        #pragma unroll
        for (int a = 0; a < 16; ++a) v[0][a] = bufA[a * 256 + t];   // stride-1: free
        #pragma unroll
        for (int a = 0; a < 16; ++a) v[1][a] = bufB[a * 256 + t];
        __syncthreads();
        #pragma unroll
        for (int i = 0; i < 4; ++i) *(v4f*)(bufA + i * 1024 + 4 * t) = t0[i];
        #pragma unroll
        for (int i = 0; i < 4; ++i) *(v4f*)(bufB + i * 1024 + 4 * t) = t1[i];
        __syncthreads();
        #pragma unroll
        for (int a = 0; a < 16; ++a) v[2][a] = bufA[a * 256 + t];
        #pragma unroll
        for (int a = 0; a < 16; ++a) v[3][a] = bufB[a * 256 + t];
    }

    // ---- Stage A: layers 0..3 (pairs in a); natural twiddle layout coalesced
    #pragma unroll
    for (int l = 0; l < 4; ++l) {
        float4 w[8];
        #pragma unroll
        for (int pc = 0; pc < 8; ++pc)
            w[pc] = tw4[l * 2048 + pc * 256 + t];
        layer_compute(v, w, 3 - l);
    }

    // ---- Transpose A->B, 2-row batches (write stride-1, read 2-way: free)
    __syncthreads();                                // stage-in reads complete
    #pragma unroll
    for (int a = 0; a < 16; ++a) bufA[a * S_AB + t] = v[0][a];
    #pragma unroll
    for (int a = 0; a < 16; ++a) bufB[a * S_AB + t] = v[1][a];
    __syncthreads();
    #pragma unroll
    for (int b = 0; b < 16; ++b) v[0][b] = bufA[thi * S_AB + b * 16 + tlo];
    #pragma unroll
    for (int b = 0; b < 16; ++b) v[1][b] = bufB[thi * S_AB + b * 16 + tlo];
    __syncthreads();
    #pragma unroll
    for (int a = 0; a < 16; ++a) bufA[a * S_AB + t] = v[2][a];
    #pragma unroll
    for (int a = 0; a < 16; ++a) bufB[a * S_AB + t] = v[3][a];
    __syncthreads();
    #pragma unroll
    for (int b = 0; b < 16; ++b) v[2][b] = bufA[thi * S_AB + b * 16 + tlo];
    #pragma unroll
    for (int b = 0; b < 16; ++b) v[3][b] = bufB[thi * S_AB + b * 16 + tlo];

    // ---- Stage B: layers 4..7 (pairs in b); coalesced permuted twiddles
    #pragma unroll
    for (int l = 4; l < 8; ++l) {
        float4 w[8];
        #pragma unroll
        for (int pc = 0; pc < 8; ++pc)
            w[pc] = nws[(l - 4) * 2048 + pc * 256 + t];
        layer_compute(v, w, 3 - (l - 4));
    }

    // ---- Transpose B->C, compact q-XOR layout (proven R12): elem (a,b,c) at
    // a*264 + b*16 + 4*((c>>2)^(b&3)) + (c&3); writes 2-way free, b128 reads
    // spread over all 8 base slots.
    {
        __syncthreads();                            // T_AB reads done
        #pragma unroll
        for (int b = 0; b < 16; ++b) {
            const int coff = 4 * (((tlo >> 2) ^ (b & 3))) + (tlo & 3);
            bufA[thi * S_AB + b * 16 + coff] = v[0][b];
            bufB[thi * S_AB + b * 16 + coff] = v[1][b];
        }
        __syncthreads();
        #pragma unroll
        for (int rr = 0; rr < 2; ++rr) {
            const float* bp = (rr ? bufB : bufA) + thi * S_AB + tlo * 16;
            #pragma unroll
            for (int q = 0; q < 4; ++q) {
                v4f c4 = *(const v4f*)(bp + 4 * (q ^ (tlo & 3)));
                v[rr][4 * q + 0] = c4.x; v[rr][4 * q + 1] = c4.y;
                v[rr][4 * q + 2] = c4.z; v[rr][4 * q + 3] = c4.w;
            }
        }
        __syncthreads();
        #pragma unroll
        for (int b = 0; b < 16; ++b) {
            const int coff = 4 * (((tlo >> 2) ^ (b & 3))) + (tlo & 3);
            bufA[thi * S_AB + b * 16 + coff] = v[2][b];
            bufB[thi * S_AB + b * 16 + coff] = v[3][b];
        }
        __syncthreads();
        #pragma unroll
        for (int rr = 2; rr < 4; ++rr) {
            const float* bp = (rr == 3 ? bufB : bufA) + thi * S_AB + tlo * 16;
            #pragma unroll
            for (int q = 0; q < 4; ++q) {
                v4f c4 = *(const v4f*)(bp + 4 * (q ^ (tlo & 3)));
                v[rr][4 * q + 0] = c4.x; v[rr][4 * q + 1] = c4.y;
                v[rr][4 * q + 2] = c4.z; v[rr][4 * q + 3] = c4.w;
            }
        }
    }

    // ---- Stage C: layers 8..11 (pairs in c)
    #pragma unroll
    for (int l = 8; l < 12; ++l) {
        float4 w[8];
        #pragma unroll
        for (int pc = 0; pc < 8; ++pc)
            w[pc] = nws[(l - 4) * 2048 + pc * 256 + t];
        layer_compute(v, w, 3 - (l - 8));
    }

    // ---- Store DIRECT (A/B vs R12's restage): thread holds elements
    // [16t, 16t+16) of each row. Plain write-back v4f stores; lanes are 64B
    // apart within an instruction (16B per sector) but L2 merges the 4
    // covering instructions into full lines (R3 counters: WRITE 139MB, no
    // amplification — the R2 disaster was the nt hint, not the pattern).
    // Saves 32 b128 LDS ops + 4 barriers per block vs the restage.
    #pragma unroll
    for (int r = 0; r < ROWS; ++r) {
        float* orow = out + (size_t)(row0 + r) * N + 16 * t;
        #pragma unroll
        for (int q = 0; q < 4; ++q) {
            v4f s4;
            s4.x = v[r][4 * q + 0]; s4.y = v[r][4 * q + 1];
            s4.z = v[r][4 * q + 2]; s4.w = v[r][4 * q + 3];
            *(v4f*)(orow + 4 * q) = s4;
        }
    }
}

// ---- Fallback (R6 structure) if workspace too small for the prepass
#define PAD_STRIDE 264
#define BUF_WORDS (16 * PAD_STRIDE)

__global__ __launch_bounds__(256, 3)
void butterfly_kernel_fb(const float* __restrict__ x,
                         const float* __restrict__ tw,
                         float* __restrict__ out) {
    __shared__ float lds[BUF_WORDS];
    const int t = threadIdx.x;
    const int thi = t >> 4, tlo = t & 15;
    const int row0 = blockIdx.x * 4;
    const float4* tw4 = (const float4*)tw;
    float v[4][16];
    #pragma unroll
    for (int r = 0; r < 4; ++r) {
        const float* xr = x + (size_t)(row0 + r) * N + t;
        #pragma unroll
        for (int a = 0; a < 16; ++a) v[r][a] = __builtin_nontemporal_load(xr + a * 256);
    }
    #pragma unroll
    for (int l = 0; l < 4; ++l) {
        float4 w[8];
        #pragma unroll
        for (int pc = 0; pc < 8; ++pc) w[pc] = tw4[l * 2048 + pc * 256 + t];
        layer_compute(v, w, 3 - l);
    }
    #pragma unroll
    for (int r = 0; r < 4; ++r) {
        #pragma unroll
        for (int a = 0; a < 16; ++a) lds[a * PAD_STRIDE + t] = v[r][a];
        __syncthreads();
        #pragma unroll
        for (int b = 0; b < 16; ++b) v[r][b] = lds[thi * PAD_STRIDE + b * 16 + tlo];
        __syncthreads();
    }
    #pragma unroll
    for (int l = 4; l < 8; ++l) {
        float4 w[8];
        #pragma unroll
        for (int pc = 0; pc < 8; ++pc) w[pc] = tw4[l * 2048 + thi * 128 + pc * 16 + tlo];
        layer_compute(v, w, 3 - (l - 4));
    }
    #pragma unroll
    for (int r = 0; r < 4; ++r) {
        #pragma unroll
        for (int b = 0; b < 16; ++b) lds[thi * PAD_STRIDE + b * 16 + tlo] = v[r][b];
        __syncthreads();
        const float* bp = &lds[thi * PAD_STRIDE + tlo * 16];
        #pragma unroll
        for (int q = 0; q < 4; ++q) {
            v4f c4 = *(const v4f*)(bp + 4 * q);
            v[r][4 * q + 0] = c4.x; v[r][4 * q + 1] = c4.y;
            v[r][4 * q + 2] = c4.z; v[r][4 * q + 3] = c4.w;
        }
        if (r != 3) __syncthreads();
    }
    #pragma unroll
    for (int l = 8; l < 12; ++l) {
        float4 w[8];
        #pragma unroll
        for (int pc = 0; pc < 8; ++pc) w[pc] = tw4[l * 2048 + thi * 128 + tlo * 8 + pc];
        layer_compute(v, w, 3 - (l - 8));
    }
    #pragma unroll
    for (int r = 0; r < 4; ++r) {
        float* orow = out + (size_t)(row0 + r) * N + 16 * t;
        #pragma unroll
        for (int q = 0; q < 4; ++q) {
            v4f s4;
            s4.x = v[r][4 * q + 0]; s4.y = v[r][4 * q + 1];
            s4.z = v[r][4 * q + 2]; s4.w = v[r][4 * q + 3];
            *(v4f*)(orow + 4 * q) = s4;
        }
    }
}

extern "C" void kernel_launch(void* const* d_in, const int* in_sizes, int n_in,
                              void* d_out, int out_size, void* d_ws, size_t ws_size,
                              hipStream_t stream) {
    const float* x  = (const float*)d_in[0];
    const float* tw = (const float*)d_in[1];
    float* out      = (float*)d_out;
    dim3 block(256);
    if (ws_size >= (size_t)NWS_F4 * 16u) {
        float4* nws = (float4*)d_ws;
        hipLaunchKernelGGL(permute_tw_kernel, dim3(64), block, 0, stream, tw, nws);
        hipLaunchKernelGGL(butterfly_kernel, dim3(BATCH / ROWS), block, 0, stream,
                           x, tw, nws, out);
    } else {
        hipLaunchKernelGGL(butterfly_kernel_fb, dim3(BATCH / 4), block, 0, stream,
                           x, tw, out);
    }
}

// Round 15
// 75.699 us; speedup vs baseline: 1.6116x; 1.1927x over previous
//
#include <hip/hip_runtime.h>

#define ROWS 4
#define N 4096
#define BATCH 8192
#define S_AB 264            // arena row stride (floats): 256+8
#define ARENA 4224          // floats per arena (16*264); 2 arenas = 33792 B
#define NWSH_BYTES (12 * 1024 * 16)   // 12 layers x 1024 h8-packs x 16B = 192KB

typedef float v4f __attribute__((ext_vector_type(4)));
typedef _Float16 h8 __attribute__((ext_vector_type(8)));

__device__ __forceinline__ void layer_compute(float (&v)[ROWS][16],
                                              const float4 (&w)[8],
                                              const int bit) {
    const int d = 1 << bit;
    #pragma unroll
    for (int pc = 0; pc < 8; ++pc) {
        const int lo = ((pc >> bit) << (bit + 1)) | (pc & (d - 1));
        const int hi = lo + d;
        #pragma unroll
        for (int r = 0; r < ROWS; ++r) {
            const float top = v[r][lo];
            const float bot = v[r][hi];
            v[r][lo] = w[pc].x * top + w[pc].y * bot;
            v[r][hi] = w[pc].z * top + w[pc].w * bot;
        }
    }
}

// ---- Prepass: ALL 12 layers -> lane-coalesced, f16-PACKED twiddles.
// One h8 (16B) holds TWO 2x2 matrices (pc=2q, 2q+1) -> per layer each thread
// issues 4 dwordx4 instead of 8 (twiddle VMEM instrs 96->48/thread) and
// twiddle L2 bytes halve. f16 rel err 2^-11 over 12 layers ~0.6% on |out|<~6
// -> absmax +~0.03 vs 0.95 threshold.
__global__ __launch_bounds__(256)
void permute_tw_h(const float* __restrict__ tw, h8* __restrict__ nwsh) {
    const int i = blockIdx.x * 256 + threadIdx.x;   // 0 .. 12287
    const int l = i >> 10;
    const int j = i & 1023;
    const int q = j >> 8;
    const int t = j & 255;
    const int a = t >> 4, c = t & 15;
    const float4* tw4 = (const float4*)tw;
    h8 o;
    #pragma unroll
    for (int e = 0; e < 2; ++e) {
        const int pc = 2 * q + e;
        const int p = (l < 4) ? (pc * 256 + t)            // stage A natural
                    : (l < 8) ? (a * 128 + pc * 16 + c)   // stage B
                              : (a * 128 + c * 8 + pc);   // stage C
        const float4 wv = tw4[l * 2048 + p];
        o[4 * e + 0] = (_Float16)wv.x; o[4 * e + 1] = (_Float16)wv.y;
        o[4 * e + 2] = (_Float16)wv.z; o[4 * e + 3] = (_Float16)wv.w;
    }
    nwsh[i] = o;
}

// R12 structure (proven best, 66.7us) with f16-packed twiddles. R14 proved
// the store restage is load-bearing (removing it: +24us) -> kept. ROWS=4 /
// (256,3) / 84-VGPR is the occupancy sweet spot (R13: ROWS=8 -> 1 block/CU,
// 2x slower).
__global__ __launch_bounds__(256, 3)
void butterfly_kernel(const float* __restrict__ x,
                      const h8* __restrict__ nwsh,
                      float* __restrict__ out) {
    __shared__ float lds[2 * ARENA];
    float* bufA = lds;
    float* bufB = lds + ARENA;
    const int t   = threadIdx.x;
    const int thi = t >> 4;
    const int tlo = t & 15;
    const int row0 = blockIdx.x * ROWS;

    float v[ROWS][16];

    // ---- Stage-in: 16 dwordx4/thread through linear LDS; rows 2/3 loads
    // issued before barrier 1 so HBM latency flies over it.
    {
        const float* r0 = x + (size_t)(row0 + 0) * N + 4 * t;
        const float* r1 = x + (size_t)(row0 + 1) * N + 4 * t;
        const float* r2 = x + (size_t)(row0 + 2) * N + 4 * t;
        const float* r3 = x + (size_t)(row0 + 3) * N + 4 * t;
        v4f t0[4], t1[4];
        #pragma unroll
        for (int i = 0; i < 4; ++i) t0[i] = *(const v4f*)(r0 + i * 1024);
        #pragma unroll
        for (int i = 0; i < 4; ++i) t1[i] = *(const v4f*)(r1 + i * 1024);
        #pragma unroll
        for (int i = 0; i < 4; ++i) *(v4f*)(bufA + i * 1024 + 4 * t) = t0[i];
        #pragma unroll
        for (int i = 0; i < 4; ++i) *(v4f*)(bufB + i * 1024 + 4 * t) = t1[i];
        #pragma unroll
        for (int i = 0; i < 4; ++i) t0[i] = *(const v4f*)(r2 + i * 1024);  // in flight
        #pragma unroll
        for (int i = 0; i < 4; ++i) t1[i] = *(const v4f*)(r3 + i * 1024);  // across bars
        __syncthreads();
        #pragma unroll
        for (int a = 0; a < 16; ++a) v[0][a] = bufA[a * 256 + t];   // stride-1: free
        #pragma unroll
        for (int a = 0; a < 16; ++a) v[1][a] = bufB[a * 256 + t];
        __syncthreads();
        #pragma unroll
        for (int i = 0; i < 4; ++i) *(v4f*)(bufA + i * 1024 + 4 * t) = t0[i];
        #pragma unroll
        for (int i = 0; i < 4; ++i) *(v4f*)(bufB + i * 1024 + 4 * t) = t1[i];
        __syncthreads();
        #pragma unroll
        for (int a = 0; a < 16; ++a) v[2][a] = bufA[a * 256 + t];
        #pragma unroll
        for (int a = 0; a < 16; ++a) v[3][a] = bufB[a * 256 + t];
    }

    // Packed twiddle fetch+unpack for layer l (4 dwordx4 + 32 v_cvt_f32_f16)
    auto ldw = [&](int l, float4 (&w)[8]) {
        #pragma unroll
        for (int q = 0; q < 4; ++q) {
            h8 pk = nwsh[l * 1024 + q * 256 + t];
            w[2 * q].x     = (float)pk[0]; w[2 * q].y     = (float)pk[1];
            w[2 * q].z     = (float)pk[2]; w[2 * q].w     = (float)pk[3];
            w[2 * q + 1].x = (float)pk[4]; w[2 * q + 1].y = (float)pk[5];
            w[2 * q + 1].z = (float)pk[6]; w[2 * q + 1].w = (float)pk[7];
        }
    };

    // ---- Stage A: layers 0..3 (pairs in a)
    #pragma unroll
    for (int l = 0; l < 4; ++l) {
        float4 w[8];
        ldw(l, w);
        layer_compute(v, w, 3 - l);
    }

    // ---- Transpose A->B, 2-row batches (write stride-1, read 2-way: free)
    __syncthreads();                                // stage-in reads complete
    #pragma unroll
    for (int a = 0; a < 16; ++a) bufA[a * S_AB + t] = v[0][a];
    #pragma unroll
    for (int a = 0; a < 16; ++a) bufB[a * S_AB + t] = v[1][a];
    __syncthreads();
    #pragma unroll
    for (int b = 0; b < 16; ++b) v[0][b] = bufA[thi * S_AB + b * 16 + tlo];
    #pragma unroll
    for (int b = 0; b < 16; ++b) v[1][b] = bufB[thi * S_AB + b * 16 + tlo];
    __syncthreads();
    #pragma unroll
    for (int a = 0; a < 16; ++a) bufA[a * S_AB + t] = v[2][a];
    #pragma unroll
    for (int a = 0; a < 16; ++a) bufB[a * S_AB + t] = v[3][a];
    __syncthreads();
    #pragma unroll
    for (int b = 0; b < 16; ++b) v[2][b] = bufA[thi * S_AB + b * 16 + tlo];
    #pragma unroll
    for (int b = 0; b < 16; ++b) v[3][b] = bufB[thi * S_AB + b * 16 + tlo];

    // ---- Stage B: layers 4..7 (pairs in b)
    #pragma unroll
    for (int l = 4; l < 8; ++l) {
        float4 w[8];
        ldw(l, w);
        layer_compute(v, w, 3 - (l - 4));
    }

    // ---- Transpose B->C, compact q-XOR layout (proven R12): elem (a,b,c) at
    // a*264 + b*16 + 4*((c>>2)^(b&3)) + (c&3); writes 2-way free, b128 reads
    // spread over all 8 base slots.
    {
        __syncthreads();                            // T_AB reads done
        #pragma unroll
        for (int b = 0; b < 16; ++b) {
            const int coff = 4 * (((tlo >> 2) ^ (b & 3))) + (tlo & 3);
            bufA[thi * S_AB + b * 16 + coff] = v[0][b];
            bufB[thi * S_AB + b * 16 + coff] = v[1][b];
        }
        __syncthreads();
        #pragma unroll
        for (int rr = 0; rr < 2; ++rr) {
            const float* bp = (rr ? bufB : bufA) + thi * S_AB + tlo * 16;
            #pragma unroll
            for (int q = 0; q < 4; ++q) {
                v4f c4 = *(const v4f*)(bp + 4 * (q ^ (tlo & 3)));
                v[rr][4 * q + 0] = c4.x; v[rr][4 * q + 1] = c4.y;
                v[rr][4 * q + 2] = c4.z; v[rr][4 * q + 3] = c4.w;
            }
        }
        __syncthreads();
        #pragma unroll
        for (int b = 0; b < 16; ++b) {
            const int coff = 4 * (((tlo >> 2) ^ (b & 3))) + (tlo & 3);
            bufA[thi * S_AB + b * 16 + coff] = v[2][b];
            bufB[thi * S_AB + b * 16 + coff] = v[3][b];
        }
        __syncthreads();
        #pragma unroll
        for (int rr = 2; rr < 4; ++rr) {
            const float* bp = (rr == 3 ? bufB : bufA) + thi * S_AB + tlo * 16;
            #pragma unroll
            for (int q = 0; q < 4; ++q) {
                v4f c4 = *(const v4f*)(bp + 4 * (q ^ (tlo & 3)));
                v[rr][4 * q + 0] = c4.x; v[rr][4 * q + 1] = c4.y;
                v[rr][4 * q + 2] = c4.z; v[rr][4 * q + 3] = c4.w;
            }
        }
    }

    // ---- Stage C: layers 8..11 (pairs in c)
    #pragma unroll
    for (int l = 8; l < 12; ++l) {
        float4 w[8];
        ldw(l, w);
        layer_compute(v, w, 3 - (l - 8));
    }

    // ---- Store restage (load-bearing, R14): XOR layout, then 1KB/wave
    // contiguous nontemporal stores. Writer f4[4T + (Q^((T>>2)&3))], reader
    // f4[(j&~3)|((j&3)^((j>>4)&3))], both 8 lanes/slot.
    {
        v4f* fA = (v4f*)bufA;
        v4f* fB = (v4f*)bufB;
        const int wsel = (t >> 2) & 3;
        __syncthreads();                            // T_BC reads done
        #pragma unroll
        for (int h = 0; h < 2; ++h) {
            #pragma unroll
            for (int rr = 0; rr < 2; ++rr) {
                v4f* f = rr ? fB : fA;
                const int r = 2 * h + rr;
                #pragma unroll
                for (int q = 0; q < 4; ++q) {
                    v4f s4;
                    s4.x = v[r][4 * q + 0]; s4.y = v[r][4 * q + 1];
                    s4.z = v[r][4 * q + 2]; s4.w = v[r][4 * q + 3];
                    f[4 * t + (q ^ wsel)] = s4;
                }
            }
            __syncthreads();
            #pragma unroll
            for (int rr = 0; rr < 2; ++rr) {
                v4f* f = rr ? fB : fA;
                const int r = 2 * h + rr;
                float* orow = out + (size_t)(row0 + r) * N;
                #pragma unroll
                for (int k = 0; k < 4; ++k) {
                    const int j = k * 256 + t;
                    v4f s4 = f[(j & ~3) | ((j & 3) ^ ((j >> 4) & 3))];
                    __builtin_nontemporal_store(s4, (v4f*)orow + j);
                }
            }
            if (h == 0) __syncthreads();
        }
    }
}

// ---- Fallback (R6 structure, f32 twiddles direct) if ws too small
#define PAD_STRIDE 264
#define BUF_WORDS (16 * PAD_STRIDE)

__global__ __launch_bounds__(256, 3)
void butterfly_kernel_fb(const float* __restrict__ x,
                         const float* __restrict__ tw,
                         float* __restrict__ out) {
    __shared__ float lds[BUF_WORDS];
    const int t = threadIdx.x;
    const int thi = t >> 4, tlo = t & 15;
    const int row0 = blockIdx.x * 4;
    const float4* tw4 = (const float4*)tw;
    float v[4][16];
    #pragma unroll
    for (int r = 0; r < 4; ++r) {
        const float* xr = x + (size_t)(row0 + r) * N + t;
        #pragma unroll
        for (int a = 0; a < 16; ++a) v[r][a] = __builtin_nontemporal_load(xr + a * 256);
    }
    #pragma unroll
    for (int l = 0; l < 4; ++l) {
        float4 w[8];
        #pragma unroll
        for (int pc = 0; pc < 8; ++pc) w[pc] = tw4[l * 2048 + pc * 256 + t];
        layer_compute(v, w, 3 - l);
    }
    #pragma unroll
    for (int r = 0; r < 4; ++r) {
        #pragma unroll
        for (int a = 0; a < 16; ++a) lds[a * PAD_STRIDE + t] = v[r][a];
        __syncthreads();
        #pragma unroll
        for (int b = 0; b < 16; ++b) v[r][b] = lds[thi * PAD_STRIDE + b * 16 + tlo];
        __syncthreads();
    }
    #pragma unroll
    for (int l = 4; l < 8; ++l) {
        float4 w[8];
        #pragma unroll
        for (int pc = 0; pc < 8; ++pc) w[pc] = tw4[l * 2048 + thi * 128 + pc * 16 + tlo];
        layer_compute(v, w, 3 - (l - 4));
    }
    #pragma unroll
    for (int r = 0; r < 4; ++r) {
        #pragma unroll
        for (int b = 0; b < 16; ++b) lds[thi * PAD_STRIDE + b * 16 + tlo] = v[r][b];
        __syncthreads();
        const float* bp = &lds[thi * PAD_STRIDE + tlo * 16];
        #pragma unroll
        for (int q = 0; q < 4; ++q) {
            v4f c4 = *(const v4f*)(bp + 4 * q);
            v[r][4 * q + 0] = c4.x; v[r][4 * q + 1] = c4.y;
            v[r][4 * q + 2] = c4.z; v[r][4 * q + 3] = c4.w;
        }
        if (r != 3) __syncthreads();
    }
    #pragma unroll
    for (int l = 8; l < 12; ++l) {
        float4 w[8];
        #pragma unroll
        for (int pc = 0; pc < 8; ++pc) w[pc] = tw4[l * 2048 + thi * 128 + tlo * 8 + pc];
        layer_compute(v, w, 3 - (l - 8));
    }
    #pragma unroll
    for (int r = 0; r < 4; ++r) {
        float* orow = out + (size_t)(row0 + r) * N + 16 * t;
        #pragma unroll
        for (int q = 0; q < 4; ++q) {
            v4f s4;
            s4.x = v[r][4 * q + 0]; s4.y = v[r][4 * q + 1];
            s4.z = v[r][4 * q + 2]; s4.w = v[r][4 * q + 3];
            *(v4f*)(orow + 4 * q) = s4;
        }
    }
}

extern "C" void kernel_launch(void* const* d_in, const int* in_sizes, int n_in,
                              void* d_out, int out_size, void* d_ws, size_t ws_size,
                              hipStream_t stream) {
    const float* x  = (const float*)d_in[0];
    const float* tw = (const float*)d_in[1];
    float* out      = (float*)d_out;
    dim3 block(256);
    if (ws_size >= (size_t)NWSH_BYTES) {
        h8* nwsh = (h8*)d_ws;
        hipLaunchKernelGGL(permute_tw_h, dim3(48), block, 0, stream, tw, nwsh);
        hipLaunchKernelGGL(butterfly_kernel, dim3(BATCH / ROWS), block, 0, stream,
                           x, nwsh, out);
    } else {
        hipLaunchKernelGGL(butterfly_kernel_fb, dim3(BATCH / 4), block, 0, stream,
                           x, tw, out);
    }
}

// Round 16
// 64.651 us; speedup vs baseline: 1.8870x; 1.1709x over previous
//
#include <hip/hip_runtime.h>

#define ROWS 4
#define N 4096
#define BATCH 8192
#define S_AB 264            // arena row stride (floats): 256+8
#define ARENA 4224          // floats per arena (16*264); 2 arenas = 33792 B
#define NWS_F4 (8 * 2048)   // permuted f32 twiddles, layers 4..11

typedef float v4f __attribute__((ext_vector_type(4)));

// Half-layer butterfly: pcs [pcb, pcb+4) with twiddles in s[0..3]. The two
// halves of a layer touch disjoint (lo,hi) pairs -> order-independent
// (decomposition verified correct in R8, absmax 0.0625).
__device__ __forceinline__ void half_layer(float (&v)[ROWS][16],
                                           const float4 (&s)[4],
                                           const int bit, const int pcb) {
    const int d = 1 << bit;
    #pragma unroll
    for (int i = 0; i < 4; ++i) {
        const int pc = pcb + i;
        const int lo = ((pc >> bit) << (bit + 1)) | (pc & (d - 1));
        const int hi = lo + d;
        #pragma unroll
        for (int r = 0; r < ROWS; ++r) {
            const float top = v[r][lo], bot = v[r][hi];
            v[r][lo] = s[i].x * top + s[i].y * bot;
            v[r][hi] = s[i].z * top + s[i].w * bot;
        }
    }
}

// ---- Prepass (R12's, f32): layers 4..11 -> lane-coalesced nws.
__global__ __launch_bounds__(256)
void permute_tw_kernel(const float* __restrict__ tw, float4* __restrict__ nws) {
    const int i = blockIdx.x * 256 + threadIdx.x;   // 0 .. 16383
    const int s  = i >> 11;                         // slot 0..7 -> layer 4+s
    const int j  = i & 2047;
    const int pc = j >> 8;
    const int a  = (j >> 4) & 15;
    const int cb = j & 15;
    const float4* tw4 = (const float4*)tw;
    const int src = (s < 4) ? (a * 128 + pc * 16 + cb)   // stage B layers 4..7
                            : (a * 128 + cb * 8 + pc);   // stage C layers 8..11
    nws[i] = tw4[(4 + s) * 2048 + src];
}

// R12 structure (champion, 66.7us; f16/R15 and no-restage/R14 and ROWS=8/R13
// all regressed) + 3-slot half-layer twiddle PREFETCH pipeline (R8 schedule,
// which was null pre-coalescing when the TA request wall bound; retried now
// that the wall is latency). launch_bounds(256,2): cap 128 by the empirical
// ~256/min_waves law; live = 64 data + 48 slots + temps ~ 120. LDS unchanged
// -> block cap still 4/CU (no R13 occupancy collapse).
__global__ __launch_bounds__(256, 2)
void butterfly_kernel(const float* __restrict__ x,
                      const float* __restrict__ tw,
                      const float4* __restrict__ nws,
                      float* __restrict__ out) {
    __shared__ float lds[2 * ARENA];
    float* bufA = lds;
    float* bufB = lds + ARENA;
    const int t   = threadIdx.x;
    const int thi = t >> 4;
    const int tlo = t & 15;
    const int row0 = blockIdx.x * ROWS;
    const float4* tw4 = (const float4*)tw;

    auto ldA = [&](int l, int pcb, float4 (&s)[4]) {     // stage A natural (coalesced)
        #pragma unroll
        for (int i = 0; i < 4; ++i) s[i] = tw4[l * 2048 + (pcb + i) * 256 + t];
    };
    auto ldN = [&](int l, int pcb, float4 (&s)[4]) {     // layers 4..11 via nws
        #pragma unroll
        for (int i = 0; i < 4; ++i) s[i] = nws[(l - 4) * 2048 + (pcb + i) * 256 + t];
    };

    float v[ROWS][16];
    float4 S0[4], S1[4], S2[4];

    // ---- Stage-in (R12): 16 dwordx4/thread through linear LDS; rows 2/3
    // loads + layer-0 twiddle prefetch fly over the stage-in barriers.
    {
        const float* r0 = x + (size_t)(row0 + 0) * N + 4 * t;
        const float* r1 = x + (size_t)(row0 + 1) * N + 4 * t;
        const float* r2 = x + (size_t)(row0 + 2) * N + 4 * t;
        const float* r3 = x + (size_t)(row0 + 3) * N + 4 * t;
        v4f t0[4], t1[4];
        #pragma unroll
        for (int i = 0; i < 4; ++i) t0[i] = *(const v4f*)(r0 + i * 1024);
        #pragma unroll
        for (int i = 0; i < 4; ++i) t1[i] = *(const v4f*)(r1 + i * 1024);
        #pragma unroll
        for (int i = 0; i < 4; ++i) *(v4f*)(bufA + i * 1024 + 4 * t) = t0[i];
        #pragma unroll
        for (int i = 0; i < 4; ++i) *(v4f*)(bufB + i * 1024 + 4 * t) = t1[i];
        #pragma unroll
        for (int i = 0; i < 4; ++i) t0[i] = *(const v4f*)(r2 + i * 1024);  // in flight
        #pragma unroll
        for (int i = 0; i < 4; ++i) t1[i] = *(const v4f*)(r3 + i * 1024);  // across bars
        __syncthreads();
        #pragma unroll
        for (int a = 0; a < 16; ++a) v[0][a] = bufA[a * 256 + t];   // stride-1: free
        #pragma unroll
        for (int a = 0; a < 16; ++a) v[1][a] = bufB[a * 256 + t];
        __syncthreads();
        #pragma unroll
        for (int i = 0; i < 4; ++i) *(v4f*)(bufA + i * 1024 + 4 * t) = t0[i];
        #pragma unroll
        for (int i = 0; i < 4; ++i) *(v4f*)(bufB + i * 1024 + 4 * t) = t1[i];
        ldA(0, 0, S0);                               // l0 twiddles fly over barrier
        ldA(0, 4, S1);
        __syncthreads();
        #pragma unroll
        for (int a = 0; a < 16; ++a) v[2][a] = bufA[a * 256 + t];
        #pragma unroll
        for (int a = 0; a < 16; ++a) v[3][a] = bufB[a * 256 + t];
    }

    // ---- Stage A: layers 0..3 (pairs in a), 3-slot pipeline: per layer
    // {load next.h0 -> free slot; compute cur.h0; load next.h1; compute cur.h1}
    ldA(1, 0, S2); half_layer(v, S0, 3, 0); ldA(1, 4, S0); half_layer(v, S1, 3, 4); // l=0
    ldA(2, 0, S1); half_layer(v, S2, 2, 0); ldA(2, 4, S2); half_layer(v, S0, 2, 4); // l=1
    ldA(3, 0, S0); half_layer(v, S1, 1, 0); ldA(3, 4, S1); half_layer(v, S2, 1, 4); // l=2
    ldN(4, 0, S2); half_layer(v, S0, 0, 0); ldN(4, 4, S0); half_layer(v, S1, 0, 4); // l=3; l4 flies over T_AB

    // ---- Transpose A->B, 2-row batches (write stride-1, read 2-way: free)
    __syncthreads();                                // stage-in reads complete
    #pragma unroll
    for (int a = 0; a < 16; ++a) bufA[a * S_AB + t] = v[0][a];
    #pragma unroll
    for (int a = 0; a < 16; ++a) bufB[a * S_AB + t] = v[1][a];
    __syncthreads();
    #pragma unroll
    for (int b = 0; b < 16; ++b) v[0][b] = bufA[thi * S_AB + b * 16 + tlo];
    #pragma unroll
    for (int b = 0; b < 16; ++b) v[1][b] = bufB[thi * S_AB + b * 16 + tlo];
    __syncthreads();
    #pragma unroll
    for (int a = 0; a < 16; ++a) bufA[a * S_AB + t] = v[2][a];
    #pragma unroll
    for (int a = 0; a < 16; ++a) bufB[a * S_AB + t] = v[3][a];
    __syncthreads();
    #pragma unroll
    for (int b = 0; b < 16; ++b) v[2][b] = bufA[thi * S_AB + b * 16 + tlo];
    #pragma unroll
    for (int b = 0; b < 16; ++b) v[3][b] = bufB[thi * S_AB + b * 16 + tlo];

    // ---- Stage B: layers 4..7 (pairs in b); S2=l4.h0, S0=l4.h1 already here
    ldN(5, 0, S1); half_layer(v, S2, 3, 0); ldN(5, 4, S2); half_layer(v, S0, 3, 4); // l=4
    ldN(6, 0, S0); half_layer(v, S1, 2, 0); ldN(6, 4, S1); half_layer(v, S2, 2, 4); // l=5
    ldN(7, 0, S2); half_layer(v, S0, 1, 0); ldN(7, 4, S0); half_layer(v, S1, 1, 4); // l=6
    ldN(8, 0, S1); half_layer(v, S2, 0, 0); ldN(8, 4, S2); half_layer(v, S0, 0, 4); // l=7; l8 flies over T_BC

    // ---- Transpose B->C, compact q-XOR layout (R12): elem (a,b,c) at
    // a*264 + b*16 + 4*((c>>2)^(b&3)) + (c&3).
    {
        __syncthreads();                            // T_AB reads done
        #pragma unroll
        for (int b = 0; b < 16; ++b) {
            const int coff = 4 * (((tlo >> 2) ^ (b & 3))) + (tlo & 3);
            bufA[thi * S_AB + b * 16 + coff] = v[0][b];
            bufB[thi * S_AB + b * 16 + coff] = v[1][b];
        }
        __syncthreads();
        #pragma unroll
        for (int rr = 0; rr < 2; ++rr) {
            const float* bp = (rr ? bufB : bufA) + thi * S_AB + tlo * 16;
            #pragma unroll
            for (int q = 0; q < 4; ++q) {
                v4f c4 = *(const v4f*)(bp + 4 * (q ^ (tlo & 3)));
                v[rr][4 * q + 0] = c4.x; v[rr][4 * q + 1] = c4.y;
                v[rr][4 * q + 2] = c4.z; v[rr][4 * q + 3] = c4.w;
            }
        }
        __syncthreads();
        #pragma unroll
        for (int b = 0; b < 16; ++b) {
            const int coff = 4 * (((tlo >> 2) ^ (b & 3))) + (tlo & 3);
            bufA[thi * S_AB + b * 16 + coff] = v[2][b];
            bufB[thi * S_AB + b * 16 + coff] = v[3][b];
        }
        __syncthreads();
        #pragma unroll
        for (int rr = 2; rr < 4; ++rr) {
            const float* bp = (rr == 3 ? bufB : bufA) + thi * S_AB + tlo * 16;
            #pragma unroll
            for (int q = 0; q < 4; ++q) {
                v4f c4 = *(const v4f*)(bp + 4 * (q ^ (tlo & 3)));
                v[rr][4 * q + 0] = c4.x; v[rr][4 * q + 1] = c4.y;
                v[rr][4 * q + 2] = c4.z; v[rr][4 * q + 3] = c4.w;
            }
        }
    }

    // ---- Stage C: layers 8..11 (pairs in c); S1=l8.h0, S2=l8.h1 already here
    ldN(9,  0, S0); half_layer(v, S1, 3, 0); ldN(9,  4, S1); half_layer(v, S2, 3, 4); // l=8
    ldN(10, 0, S2); half_layer(v, S0, 2, 0); ldN(10, 4, S0); half_layer(v, S1, 2, 4); // l=9
    ldN(11, 0, S1); half_layer(v, S2, 1, 0); ldN(11, 4, S2); half_layer(v, S0, 1, 4); // l=10
                    half_layer(v, S1, 0, 0);                 half_layer(v, S2, 0, 4); // l=11

    // ---- Store restage (load-bearing, R14): XOR layout, then 1KB/wave
    // contiguous nontemporal stores.
    {
        v4f* fA = (v4f*)bufA;
        v4f* fB = (v4f*)bufB;
        const int wsel = (t >> 2) & 3;
        __syncthreads();                            // T_BC reads done
        #pragma unroll
        for (int h = 0; h < 2; ++h) {
            #pragma unroll
            for (int rr = 0; rr < 2; ++rr) {
                v4f* f = rr ? fB : fA;
                const int r = 2 * h + rr;
                #pragma unroll
                for (int q = 0; q < 4; ++q) {
                    v4f s4;
                    s4.x = v[r][4 * q + 0]; s4.y = v[r][4 * q + 1];
                    s4.z = v[r][4 * q + 2]; s4.w = v[r][4 * q + 3];
                    f[4 * t + (q ^ wsel)] = s4;
                }
            }
            __syncthreads();
            #pragma unroll
            for (int rr = 0; rr < 2; ++rr) {
                v4f* f = rr ? fB : fA;
                const int r = 2 * h + rr;
                float* orow = out + (size_t)(row0 + r) * N;
                #pragma unroll
                for (int k = 0; k < 4; ++k) {
                    const int j = k * 256 + t;
                    v4f s4 = f[(j & ~3) | ((j & 3) ^ ((j >> 4) & 3))];
                    __builtin_nontemporal_store(s4, (v4f*)orow + j);
                }
            }
            if (h == 0) __syncthreads();
        }
    }
}

// ---- Fallback (R6 structure) if workspace too small for the prepass
#define PAD_STRIDE 264
#define BUF_WORDS (16 * PAD_STRIDE)

__device__ __forceinline__ void layer16(float (&v)[4][16], const float4 (&w)[8], const int bit) {
    const int d = 1 << bit;
    #pragma unroll
    for (int pc = 0; pc < 8; ++pc) {
        const int lo = ((pc >> bit) << (bit + 1)) | (pc & (d - 1));
        const int hi = lo + d;
        #pragma unroll
        for (int r = 0; r < 4; ++r) {
            const float top = v[r][lo], bot = v[r][hi];
            v[r][lo] = w[pc].x * top + w[pc].y * bot;
            v[r][hi] = w[pc].z * top + w[pc].w * bot;
        }
    }
}

__global__ __launch_bounds__(256, 3)
void butterfly_kernel_fb(const float* __restrict__ x,
                         const float* __restrict__ tw,
                         float* __restrict__ out) {
    __shared__ float lds[BUF_WORDS];
    const int t = threadIdx.x;
    const int thi = t >> 4, tlo = t & 15;
    const int row0 = blockIdx.x * 4;
    const float4* tw4 = (const float4*)tw;
    float v[4][16];
    #pragma unroll
    for (int r = 0; r < 4; ++r) {
        const float* xr = x + (size_t)(row0 + r) * N + t;
        #pragma unroll
        for (int a = 0; a < 16; ++a) v[r][a] = __builtin_nontemporal_load(xr + a * 256);
    }
    #pragma unroll
    for (int l = 0; l < 4; ++l) {
        float4 w[8];
        #pragma unroll
        for (int pc = 0; pc < 8; ++pc) w[pc] = tw4[l * 2048 + pc * 256 + t];
        layer16(v, w, 3 - l);
    }
    #pragma unroll
    for (int r = 0; r < 4; ++r) {
        #pragma unroll
        for (int a = 0; a < 16; ++a) lds[a * PAD_STRIDE + t] = v[r][a];
        __syncthreads();
        #pragma unroll
        for (int b = 0; b < 16; ++b) v[r][b] = lds[thi * PAD_STRIDE + b * 16 + tlo];
        __syncthreads();
    }
    #pragma unroll
    for (int l = 4; l < 8; ++l) {
        float4 w[8];
        #pragma unroll
        for (int pc = 0; pc < 8; ++pc) w[pc] = tw4[l * 2048 + thi * 128 + pc * 16 + tlo];
        layer16(v, w, 3 - (l - 4));
    }
    #pragma unroll
    for (int r = 0; r < 4; ++r) {
        #pragma unroll
        for (int b = 0; b < 16; ++b) lds[thi * PAD_STRIDE + b * 16 + tlo] = v[r][b];
        __syncthreads();
        const float* bp = &lds[thi * PAD_STRIDE + tlo * 16];
        #pragma unroll
        for (int q = 0; q < 4; ++q) {
            v4f c4 = *(const v4f*)(bp + 4 * q);
            v[r][4 * q + 0] = c4.x; v[r][4 * q + 1] = c4.y;
            v[r][4 * q + 2] = c4.z; v[r][4 * q + 3] = c4.w;
        }
        if (r != 3) __syncthreads();
    }
    #pragma unroll
    for (int l = 8; l < 12; ++l) {
        float4 w[8];
        #pragma unroll
        for (int pc = 0; pc < 8; ++pc) w[pc] = tw4[l * 2048 + thi * 128 + tlo * 8 + pc];
        layer16(v, w, 3 - (l - 8));
    }
    #pragma unroll
    for (int r = 0; r < 4; ++r) {
        float* orow = out + (size_t)(row0 + r) * N + 16 * t;
        #pragma unroll
        for (int q = 0; q < 4; ++q) {
            v4f s4;
            s4.x = v[r][4 * q + 0]; s4.y = v[r][4 * q + 1];
            s4.z = v[r][4 * q + 2]; s4.w = v[r][4 * q + 3];
            *(v4f*)(orow + 4 * q) = s4;
        }
    }
}

extern "C" void kernel_launch(void* const* d_in, const int* in_sizes, int n_in,
                              void* d_out, int out_size, void* d_ws, size_t ws_size,
                              hipStream_t stream) {
    const float* x  = (const float*)d_in[0];
    const float* tw = (const float*)d_in[1];
    float* out      = (float*)d_out;
    dim3 block(256);
    if (ws_size >= (size_t)NWS_F4 * 16u) {
        float4* nws = (float4*)d_ws;
        hipLaunchKernelGGL(permute_tw_kernel, dim3(64), block, 0, stream, tw, nws);
        hipLaunchKernelGGL(butterfly_kernel, dim3(BATCH / ROWS), block, 0, stream,
                           x, tw, nws, out);
    } else {
        hipLaunchKernelGGL(butterfly_kernel_fb, dim3(BATCH / 4), block, 0, stream,
                           x, tw, out);
    }
}